// Round 19
// baseline (61.884 us; speedup 1.0000x reference)
//
#include <hip/hip_runtime.h>
#include <hip/hip_bf16.h>
#include <math.h>

#define EPS_F 1e-7f

constexpr int Bn = 128, Sn = 1024, Dn = 256, ATTn = 128, QDn = 128;
constexpr int Mn = Bn * Sn;          // 131072 rows
constexpr int BM = 128;              // rows per block (8 waves x 16 rows)
constexpr int NBLK = Mn / BM;        // 1024 blocks
constexpr int NJ = ATTn / 16;        // 8 column fragments

typedef short short8 __attribute__((ext_vector_type(8)));
typedef float f32x4  __attribute__((ext_vector_type(4)));

// Exact truncation split of A: f = hi + r exactly, lo = bf16_rne(r).
// (ah+al)*bh preserves A to ~2^-17; B carries bf16-RNE error (2^-10).
__device__ inline void split_bf(float f, ushort& hi, ushort& lo) {
    uint fb = __float_as_uint(f);
    hi = (ushort)(fb >> 16);
    float hf = __uint_as_float(fb & 0xffff0000u);
    float lf = f - hf;                       // exact
    __hip_bfloat16 lb = __float2bfloat16(lf);
    __builtin_memcpy(&lo, &lb, 2);
}

__device__ inline float hi2f(short h) {
    return __uint_as_float(((uint)(ushort)h) << 16);
}

__device__ inline float tanh_fast(float x) {
    float cx = fminf(9.0f, fmaxf(-9.0f, x));
    float e = __builtin_amdgcn_exp2f(cx * 2.8853900817779268f);  // e^{2x}
    return (e - 1.0f) * __builtin_amdgcn_rcpf(e + 1.0f);
}

// async global->LDS, 16B per lane. LDS dest is wave-uniform base + lane*16;
// the GLOBAL source is per-lane.
__device__ inline void gload_lds16(const void* g, void* lds_base) {
    __builtin_amdgcn_global_load_lds(
        (const __attribute__((address_space(1))) unsigned int*)g,
        (__attribute__((address_space(3))) unsigned int*)lds_base, 16, 0, 0);
}

#define MFMA_BF16 __builtin_amdgcn_mfma_f32_16x16x32_bf16
#define PIN() __builtin_amdgcn_sched_barrier(0)

// ---------------- ws layout (bytes) ----------------
// [0,512)              u (128 f32)
// [512,66048)          Bhi (4096 chunks x 8 bf16, RNE)
// [66048,1114624)      P   (1024 blk * 256 d f32)
// [1114624,1118720)    den (1024 f32)

// Merged prep: block 0 computes u = W_u @ query; blocks 1..16 build the
// MFMA-B-fragment-ordered bf16 (RNE) copy of W.
// Fragment (ks,j): lane l holds col = 16j+(l&15), k = 32ks+(l>>4)*8+i.
// Chunk index = (ks*8 + j)*64 + lane.
__global__ __launch_bounds__(256) void k_prep(
    const float* __restrict__ Wu, const float* __restrict__ q,
    float* __restrict__ u,
    const float* __restrict__ W,
    ushort* __restrict__ Bhi)
{
    if (blockIdx.x == 0) {
        __shared__ float qs[QDn];
        int t = threadIdx.x;
        if (t < QDn) qs[t] = q[t];
        __syncthreads();
        if (t < ATTn) {
            float acc = 0.f;
            #pragma unroll 8
            for (int j = 0; j < QDn; ++j) acc += Wu[t * QDn + j] * qs[j];
            u[t] = acc;
        }
        return;
    }
    int gid  = (blockIdx.x - 1) * 256 + threadIdx.x;   // 0..4095
    int lane = gid & 63;
    int j    = (gid >> 6) & 7;
    int ks   = gid >> 9;
    int col  = j * 16 + (lane & 15);
    int kb   = ks * 32 + (lane >> 4) * 8;
    #pragma unroll
    for (int i = 0; i < 8; ++i) {
        float f = W[(size_t)(kb + i) * ATTn + col];
        __hip_bfloat16 h = __float2bfloat16(f);   // RNE
        ushort hu; __builtin_memcpy(&hu, &h, 2);
        Bhi[(size_t)gid * 8 + i] = hu;
    }
}

// ---------- k_scores helpers ----------
// LDS map (float4 chunks): B0=[0,1024) B1=[1024,2048) A0=[2048,3072) A1=[3072,4096)

// Stage one B quarter (2 ksteps, 16 KB). Linear, lane-contiguous.
__device__ __forceinline__ void stage_Bq(
    float4* bbuf, const ushort* __restrict__ Bhi, int q, int t, int w)
{
    #pragma unroll
    for (int i = 0; i < 2; ++i) {
        int c = i * 512 + t;             // 0..1023
        gload_lds16(Bhi + (size_t)(q * 1024 + c) * 8, bbuf + (i * 512 + w * 64));
    }
}

// Stage one A tile (128 rows x 32 k f32, 16 KB).
// LDS slot s holds logical chunk (row = s>>3, c = (s&7) ^ (row&7)) via
// inverse-swizzled per-lane global SOURCE (linear DMA dest, rule #21).
__device__ __forceinline__ void stage_A(
    float4* abuf, const float* __restrict__ key, int row0, int ks, int t, int w)
{
    #pragma unroll
    for (int i = 0; i < 2; ++i) {
        int s   = i * 512 + t;           // 0..1023
        int row = s >> 3;
        int cl  = (s & 7) ^ (row & 7);
        const float* src = key + (size_t)(row0 + row) * Dn + ks * 32 + cl * 4;
        gload_lds16(src, abuf + (i * 512 + w * 64));
    }
}

// One k-step: A fragment from LDS (swizzled read) -> split bf16 hi/lo;
// KEEP the hi fragment in ahk[KS] (phase-2 source). 8 column fragments x 2
// MFMAs with 3-deep circular bh prefetch.
template<int KS>
__device__ __forceinline__ void compute_ks(
    const float4* abuf, const float4* bbuf,
    f32x4 (&acc)[NJ], short8 (&ahk)[8], int w, int lane)
{
    const int l15 = lane & 15, lg = lane >> 4;
    const int r = w * 16 + l15;
    float4 a0 = abuf[r * 8 + ((lg * 2)     ^ (r & 7))];
    float4 a1 = abuf[r * 8 + ((lg * 2 + 1) ^ (r & 7))];
    short8 ah, al;
    {
        float f[8] = {a0.x, a0.y, a0.z, a0.w, a1.x, a1.y, a1.z, a1.w};
        #pragma unroll
        for (int i = 0; i < 8; ++i) {
            ushort h, l;
            split_bf(f[i], h, l);
            ah[i] = (short)h; al[i] = (short)l;
        }
    }
    ahk[KS] = ah;                        // static index: stays in VGPRs
    const float4* Bh = bbuf + (KS & 1) * 512 + lane;
    short8 bh[3];
    bh[0] = *(const short8*)(Bh);
    bh[1] = *(const short8*)(Bh + 64);
    bh[2] = *(const short8*)(Bh + 128);
    __builtin_amdgcn_s_setprio(1);
    #pragma unroll
    for (int j = 0; j < NJ; ++j) {
        const int slot = j % 3;          // static after unroll
        short8 cbh = bh[slot];
        if (j + 3 < NJ)
            bh[slot] = *(const short8*)(Bh + (j + 3) * 64);
        acc[j] = MFMA_BF16(ah, cbh, acc[j], 0, 0, 0);
        acc[j] = MFMA_BF16(al, cbh, acc[j], 0, 0, 0);
    }
    __builtin_amdgcn_s_setprio(0);
}

// Fused scores + REGISTER-retained phase 2 (no key re-read). Round-16
// staging schedule (best measured). 64 KB LDS -> 2 blocks/CU.
__global__ __launch_bounds__(512, 4) void k_scores(
    const float*  __restrict__ key,
    const ushort* __restrict__ Bhi,
    const float*  __restrict__ bias, const float* __restrict__ u,
    const int*    __restrict__ mask,
    float* __restrict__ P, float* __restrict__ den)
{
    __shared__ float4 smem[4096];        // 64 KB
    float4* B0 = smem;
    float4* B1 = smem + 1024;
    float4* A0 = smem + 2048;
    float4* A1 = smem + 3072;
    float*  esp   = (float*)smem;        // [128] scores (aliased after loop)
    float*  partp = (float*)(smem + 64); // [8][256] f32 partials

    const int t    = threadIdx.x;        // 0..511
    const int lane = t & 63;
    const int w    = t >> 6;             // wave 0..7 -> rows w*16..w*16+15
    const int gb   = blockIdx.x;
    const int row0 = gb * BM;
    const int l15  = lane & 15;
    const int lg   = lane >> 4;

    f32x4 acc[NJ];
    #pragma unroll
    for (int j = 0; j < NJ; ++j) acc[j] = (f32x4){0.f, 0.f, 0.f, 0.f};
    short8 ahk[8];                       // kept bf16-hi A fragments

    // prologue: B quarter 0 + A tile 0
    stage_Bq(B0, Bhi, 0, t, w);
    stage_A(A0, key, row0, 0, t, w);
    __syncthreads();

    // ks0
    stage_Bq(B1, Bhi, 1, t, w);
    stage_A(A1, key, row0, 1, t, w);
    PIN();
    compute_ks<0>(A0, B0, acc, ahk, w, lane);
    __syncthreads();
    // ks1
    stage_A(A0, key, row0, 2, t, w);
    PIN();
    compute_ks<1>(A1, B0, acc, ahk, w, lane);
    __syncthreads();
    // ks2
    stage_Bq(B0, Bhi, 2, t, w);
    stage_A(A1, key, row0, 3, t, w);
    PIN();
    compute_ks<2>(A0, B1, acc, ahk, w, lane);
    __syncthreads();
    // ks3
    stage_A(A0, key, row0, 4, t, w);
    PIN();
    compute_ks<3>(A1, B1, acc, ahk, w, lane);
    __syncthreads();
    // ks4
    stage_Bq(B1, Bhi, 3, t, w);
    stage_A(A1, key, row0, 5, t, w);
    PIN();
    compute_ks<4>(A0, B0, acc, ahk, w, lane);
    __syncthreads();
    // ks5
    stage_A(A0, key, row0, 6, t, w);
    PIN();
    compute_ks<5>(A1, B0, acc, ahk, w, lane);
    __syncthreads();
    // ks6
    stage_A(A1, key, row0, 7, t, w);
    PIN();
    compute_ks<6>(A0, B1, acc, ahk, w, lane);
    __syncthreads();
    // ks7
    compute_ks<7>(A1, B1, acc, ahk, w, lane);
    __syncthreads();                     // smem dead; reusable

    // Epilogue: s(row) = sum_col tanh(acc+bias)*u; e = exp(s)*mask.
    // C/D layout: col = 16j + l15, row(frag-local) = lg*4 + reg.
    float s4[4] = {0.f, 0.f, 0.f, 0.f};
    #pragma unroll
    for (int j = 0; j < NJ; ++j) {
        int col = j * 16 + l15;
        float bv = bias[col], uvv = u[col];
        #pragma unroll
        for (int reg = 0; reg < 4; ++reg)
            s4[reg] += tanh_fast(acc[j][reg] + bv) * uvv;
    }
    #pragma unroll
    for (int reg = 0; reg < 4; ++reg) {
        float s = s4[reg];
        s += __shfl_xor(s, 1);
        s += __shfl_xor(s, 2);
        s += __shfl_xor(s, 4);
        s += __shfl_xor(s, 8);
        if (l15 == 0) {
            int rl = w * 16 + lg * 4 + reg;
            esp[rl] = __builtin_amdgcn_exp2f(s * 1.4426950408889634f)
                      * (float)mask[row0 + rl];
        }
    }
    __syncthreads();

    // block-partial denominator (128 scores)
    if (t < 64) {
        float v = esp[t] + esp[t + 64];
        #pragma unroll
        for (int m = 1; m < 64; m <<= 1) v += __shfl_xor(v, m);
        if (t == 0) den[gb] = v;
    }

    // phase 2 FROM REGISTERS: P[d] = sum_rows e(row) * key_hi(row,d).
    // Thread (w,l15,lg) holds row w*16+l15, d = ks*32 + lg*8 + i.
    // Reduce over the 16-lane row group (xor 1,2,4,8 -> DPP-speed).
    {
        float e = esp[w * 16 + l15];
        #pragma unroll
        for (int ks = 0; ks < 8; ++ks) {
            float p[8];
            #pragma unroll
            for (int i = 0; i < 8; ++i)
                p[i] = e * hi2f(ahk[ks][i]);
            #pragma unroll
            for (int i = 0; i < 8; ++i) {
                p[i] += __shfl_xor(p[i], 1);
                p[i] += __shfl_xor(p[i], 2);
                p[i] += __shfl_xor(p[i], 4);
                p[i] += __shfl_xor(p[i], 8);
            }
            if (l15 == 0) {
                float* dst = &partp[w * 256 + ks * 32 + lg * 8];
                *(float4*)(dst)     = make_float4(p[0], p[1], p[2], p[3]);
                *(float4*)(dst + 4) = make_float4(p[4], p[5], p[6], p[7]);
            }
        }
    }
    __syncthreads();

    if (t < 64) {
        float4 o = *(float4*)&partp[t * 4];
        #pragma unroll
        for (int wv = 1; wv < 8; ++wv) {
            float4 p = *(float4*)&partp[wv * 256 + t * 4];
            o.x += p.x; o.y += p.y; o.z += p.z; o.w += p.w;
        }
        *(float4*)(P + (size_t)gb * Dn + t * 4) = o;
    }
}

// combine 8 block-partials per batch, normalize.
__global__ __launch_bounds__(256) void k_final(const float* __restrict__ P,
        const float* __restrict__ den, float* __restrict__ out) {
    int b = blockIdx.x, t = threadIdx.x;
    float dtot = 0.f;
    #pragma unroll
    for (int k = 0; k < 8; ++k) dtot += den[b * 8 + k];
    float o = 0.f;
    #pragma unroll
    for (int k = 0; k < 8; ++k) o += P[(size_t)(b * 8 + k) * Dn + t];
    out[(size_t)b * Dn + t] = o / (dtot + EPS_F);
}

extern "C" void kernel_launch(void* const* d_in, const int* in_sizes, int n_in,
                              void* d_out, int out_size, void* d_ws, size_t ws_size,
                              hipStream_t stream) {
    const float* key   = (const float*)d_in[0];
    const float* query = (const float*)d_in[1];
    const int*   mask  = (const int*)d_in[2];
    const float* W     = (const float*)d_in[3];
    const float* bias  = (const float*)d_in[4];
    const float* Wu    = (const float*)d_in[5];
    float* out = (float*)d_out;

    char* ws = (char*)d_ws;
    float*  u   = (float*)(ws);
    ushort* Bhi = (ushort*)(ws + 512);
    float*  Pp  = (float*)(ws + 66048);
    float*  den = (float*)(ws + 1114624);

    hipLaunchKernelGGL(k_prep,   dim3(17),   dim3(256), 0, stream, Wu, query, u, W, Bhi);
    hipLaunchKernelGGL(k_scores, dim3(NBLK), dim3(512), 0, stream,
                       key, Bhi, bias, u, mask, Pp, den);
    hipLaunchKernelGGL(k_final,  dim3(Bn),   dim3(256), 0, stream, Pp, den, out);
}

// Round 20
// 51.728 us; speedup vs baseline: 1.1963x; 1.1963x over previous
//
#include <hip/hip_runtime.h>
#include <hip/hip_bf16.h>
#include <math.h>

#define EPS_F 1e-7f

constexpr int Bn = 128, Sn = 1024, Dn = 256, ATTn = 128, QDn = 128;
constexpr int Mn = Bn * Sn;          // 131072 rows
constexpr int BM = 128;              // rows per block (8 waves x 16 rows)
constexpr int NBLK = Mn / BM;        // 1024 blocks
constexpr int NJ = ATTn / 16;        // 8 column fragments

typedef short short8 __attribute__((ext_vector_type(8)));
typedef float f32x4  __attribute__((ext_vector_type(4)));

// Exact truncation split of A: f = hi + r exactly, lo = bf16_rne(r).
// (ah+al)*bh preserves A to ~2^-17; B carries bf16-RNE error (2^-10).
__device__ inline void split_bf(float f, ushort& hi, ushort& lo) {
    uint fb = __float_as_uint(f);
    hi = (ushort)(fb >> 16);
    float hf = __uint_as_float(fb & 0xffff0000u);
    float lf = f - hf;                       // exact
    __hip_bfloat16 lb = __float2bfloat16(lf);
    __builtin_memcpy(&lo, &lb, 2);
}

__device__ inline float tanh_fast(float x) {
    float cx = fminf(9.0f, fmaxf(-9.0f, x));
    float e = __builtin_amdgcn_exp2f(cx * 2.8853900817779268f);  // e^{2x}
    return (e - 1.0f) * __builtin_amdgcn_rcpf(e + 1.0f);
}

// async global->LDS, 16B per lane. LDS dest is wave-uniform base + lane*16;
// the GLOBAL source is per-lane.
__device__ inline void gload_lds16(const void* g, void* lds_base) {
    __builtin_amdgcn_global_load_lds(
        (const __attribute__((address_space(1))) unsigned int*)g,
        (__attribute__((address_space(3))) unsigned int*)lds_base, 16, 0, 0);
}

#define MFMA_BF16 __builtin_amdgcn_mfma_f32_16x16x32_bf16
#define PIN() __builtin_amdgcn_sched_barrier(0)

// ---------------- ws layout (bytes) ----------------
// [0,512)              u (128 f32)
// [512,66048)          Bhi (4096 chunks x 8 bf16, RNE)
// [66048,1114624)      P   (1024 blk * 256 d f32)
// [1114624,1118720)    den (1024 f32)

// Merged prep: block 0 computes u = W_u @ query; blocks 1..64 build the
// MFMA-B-fragment-ordered bf16 (RNE) copy of W, 2 elements per thread
// (short gather chains -> low serial latency).
// Fragment (ks,j): lane l holds col = 16j+(l&15), k = 32ks+(l>>4)*8+i.
// Chunk index = (ks*8 + j)*64 + lane.
__global__ __launch_bounds__(256) void k_prep(
    const float* __restrict__ Wu, const float* __restrict__ q,
    float* __restrict__ u,
    const float* __restrict__ W,
    ushort* __restrict__ Bhi)
{
    if (blockIdx.x == 0) {
        __shared__ float qs[QDn];
        int t = threadIdx.x;
        if (t < QDn) qs[t] = q[t];
        __syncthreads();
        if (t < ATTn) {
            float acc = 0.f;
            #pragma unroll 8
            for (int j = 0; j < QDn; ++j) acc += Wu[t * QDn + j] * qs[j];
            u[t] = acc;
        }
        return;
    }
    int gid2 = (blockIdx.x - 1) * 256 + threadIdx.x;   // 0..16383
    int gid  = gid2 >> 2;            // chunk 0..4095
    int i0   = (gid2 & 3) * 2;       // element pair within chunk
    int lane = gid & 63;
    int j    = (gid >> 6) & 7;
    int ks   = gid >> 9;
    int col  = j * 16 + (lane & 15);
    int kb   = ks * 32 + (lane >> 4) * 8;
    #pragma unroll
    for (int i = i0; i < i0 + 2; ++i) {
        float f = W[(size_t)(kb + i) * ATTn + col];
        __hip_bfloat16 h = __float2bfloat16(f);   // RNE
        ushort hu; __builtin_memcpy(&hu, &h, 2);
        Bhi[(size_t)gid * 8 + i] = hu;
    }
}

// ---------- k_scores helpers ----------
// LDS map (float4 chunks): B0=[0,1024) B1=[1024,2048) A0=[2048,3072) A1=[3072,4096)

// Stage one B quarter (2 ksteps, 16 KB) into bbuf. Linear, lane-contiguous.
__device__ __forceinline__ void stage_Bq(
    float4* bbuf, const ushort* __restrict__ Bhi, int q, int t, int w)
{
    #pragma unroll
    for (int i = 0; i < 2; ++i) {
        int c = i * 512 + t;             // 0..1023
        gload_lds16(Bhi + (size_t)(q * 1024 + c) * 8, bbuf + (i * 512 + w * 64));
    }
}

// Stage one A tile (128 rows x 32 k f32, 16 KB) into abuf.
// LDS slot s holds logical chunk (row = s>>3, c = (s&7) ^ (row&7)) via
// inverse-swizzled per-lane global SOURCE (linear DMA dest, rule #21).
// Per wave-instruction: 8 full rows x 128 B contiguous line slices.
__device__ __forceinline__ void stage_A(
    float4* abuf, const float* __restrict__ key, int row0, int ks, int t, int w)
{
    #pragma unroll
    for (int i = 0; i < 2; ++i) {
        int s   = i * 512 + t;           // 0..1023
        int row = s >> 3;
        int cl  = (s & 7) ^ (row & 7);
        const float* src = key + (size_t)(row0 + row) * Dn + ks * 32 + cl * 4;
        gload_lds16(src, abuf + (i * 512 + w * 64));
    }
}

// One k-step: A fragment from LDS (swizzled read) -> split bf16 hi/lo,
// 8 column fragments x 2 MFMAs with 3-deep circular bh prefetch.
template<int KS>
__device__ __forceinline__ void compute_ks(
    const float4* abuf, const float4* bbuf,
    f32x4 (&acc)[NJ], int w, int lane)
{
    const int l15 = lane & 15, lg = lane >> 4;
    const int r = w * 16 + l15;
    float4 a0 = abuf[r * 8 + ((lg * 2)     ^ (r & 7))];
    float4 a1 = abuf[r * 8 + ((lg * 2 + 1) ^ (r & 7))];
    short8 ah, al;
    {
        float f[8] = {a0.x, a0.y, a0.z, a0.w, a1.x, a1.y, a1.z, a1.w};
        #pragma unroll
        for (int i = 0; i < 8; ++i) {
            ushort h, l;
            split_bf(f[i], h, l);
            ah[i] = (short)h; al[i] = (short)l;
        }
    }
    const float4* Bh = bbuf + (KS & 1) * 512 + lane;
    short8 bh[3];
    bh[0] = *(const short8*)(Bh);
    bh[1] = *(const short8*)(Bh + 64);
    bh[2] = *(const short8*)(Bh + 128);
    __builtin_amdgcn_s_setprio(1);
    #pragma unroll
    for (int j = 0; j < NJ; ++j) {
        const int slot = j % 3;          // static after unroll
        short8 cbh = bh[slot];
        if (j + 3 < NJ)
            bh[slot] = *(const short8*)(Bh + (j + 3) * 64);
        acc[j] = MFMA_BF16(ah, cbh, acc[j], 0, 0, 0);
        acc[j] = MFMA_BF16(al, cbh, acc[j], 0, 0, 0);
    }
    __builtin_amdgcn_s_setprio(0);
}

// Fused scores + partial weighted sums. ALL key traffic via global_load_lds
// with line-contiguous sources; waves touch only LDS in the hot loop.
// A tiles (16 KB) double-buffered per kstep; B quarters (16 KB) double-
// buffered, staged 2 ksteps ahead. 64 KB LDS -> 2 blocks/CU (16 waves/CU).
__global__ __launch_bounds__(512, 4) void k_scores(
    const float*  __restrict__ key,
    const ushort* __restrict__ Bhi,
    const float*  __restrict__ bias, const float* __restrict__ u,
    const int*    __restrict__ mask,
    float* __restrict__ P, float* __restrict__ den)
{
    __shared__ float4 smem[4096];        // 64 KB
    float4* B0 = smem;
    float4* B1 = smem + 1024;
    float4* A0 = smem + 2048;
    float4* A1 = smem + 3072;
    float*  esp   = (float*)smem;        // [128] scores (aliased after loop)
    float4* partp = smem + 64;           // [8][64] float4 partials

    const int t    = threadIdx.x;        // 0..511
    const int lane = t & 63;
    const int w    = t >> 6;             // wave 0..7 -> rows w*16..w*16+15
    const int gb   = blockIdx.x;
    const int row0 = gb * BM;
    const int l15  = lane & 15;
    const int lg   = lane >> 4;

    f32x4 acc[NJ];
    #pragma unroll
    for (int j = 0; j < NJ; ++j) acc[j] = (f32x4){0.f, 0.f, 0.f, 0.f};

    // prologue: B quarter 0 + A tile 0
    stage_Bq(B0, Bhi, 0, t, w);
    stage_A(A0, key, row0, 0, t, w);
    __syncthreads();

    // ks0: stage Bq1 + A1, compute(A0,B0)
    stage_Bq(B1, Bhi, 1, t, w);
    stage_A(A1, key, row0, 1, t, w);
    PIN();
    compute_ks<0>(A0, B0, acc, w, lane);
    __syncthreads();
    // ks1
    stage_A(A0, key, row0, 2, t, w);
    PIN();
    compute_ks<1>(A1, B0, acc, w, lane);
    __syncthreads();
    // ks2: B0 free (ks0/ks1 done) -> stage Bq2
    stage_Bq(B0, Bhi, 2, t, w);
    stage_A(A1, key, row0, 3, t, w);
    PIN();
    compute_ks<2>(A0, B1, acc, w, lane);
    __syncthreads();
    // ks3
    stage_A(A0, key, row0, 4, t, w);
    PIN();
    compute_ks<3>(A1, B1, acc, w, lane);
    __syncthreads();
    // ks4: B1 free -> stage Bq3
    stage_Bq(B1, Bhi, 3, t, w);
    stage_A(A1, key, row0, 5, t, w);
    PIN();
    compute_ks<4>(A0, B0, acc, w, lane);
    __syncthreads();
    // ks5
    stage_A(A0, key, row0, 6, t, w);
    PIN();
    compute_ks<5>(A1, B0, acc, w, lane);
    __syncthreads();
    // ks6
    stage_A(A1, key, row0, 7, t, w);
    PIN();
    compute_ks<6>(A0, B1, acc, w, lane);
    __syncthreads();
    // ks7
    compute_ks<7>(A1, B1, acc, w, lane);
    __syncthreads();                     // smem dead; reusable

    // Epilogue: s(row) = sum_col tanh(acc+bias)*u; e = exp(s)*mask.
    // C/D layout: col = 16j + l15, row(frag-local) = lg*4 + reg.
    float s4[4] = {0.f, 0.f, 0.f, 0.f};
    #pragma unroll
    for (int j = 0; j < NJ; ++j) {
        int col = j * 16 + l15;
        float bv = bias[col], uvv = u[col];
        #pragma unroll
        for (int reg = 0; reg < 4; ++reg)
            s4[reg] += tanh_fast(acc[j][reg] + bv) * uvv;
    }
    #pragma unroll
    for (int reg = 0; reg < 4; ++reg) {
        float s = s4[reg];
        s += __shfl_xor(s, 1);
        s += __shfl_xor(s, 2);
        s += __shfl_xor(s, 4);
        s += __shfl_xor(s, 8);
        if (l15 == 0) {
            int rl = w * 16 + lg * 4 + reg;
            esp[rl] = __builtin_amdgcn_exp2f(s * 1.4426950408889634f)
                      * (float)mask[row0 + rl];
        }
    }
    __syncthreads();

    // block-partial denominator (128 scores)
    if (t < 64) {
        float v = esp[t] + esp[t + 64];
        #pragma unroll
        for (int m = 1; m < 64; m <<= 1) v += __shfl_xor(v, m);
        if (t == 0) den[gb] = v;
    }

    // phase 2: wave w sums its 16 rows over all d (tile is L2/L3-hot;
    // lane-contiguous reads).
    {
        const float4* kt = (const float4*)(key + (size_t)(row0 + w * 16) * Dn);
        float4 a2 = make_float4(0.f, 0.f, 0.f, 0.f);
        #pragma unroll 4
        for (int s2 = 0; s2 < 16; ++s2) {
            float wv   = esp[w * 16 + s2];
            float4 kvv = kt[(size_t)s2 * 64 + lane];
            a2.x += wv * kvv.x; a2.y += wv * kvv.y;
            a2.z += wv * kvv.z; a2.w += wv * kvv.w;
        }
        partp[w * 64 + lane] = a2;
    }
    __syncthreads();

    if (t < 64) {
        float4 o = partp[t];
        #pragma unroll
        for (int wv = 1; wv < 8; ++wv) {
            float4 p = partp[wv * 64 + t];
            o.x += p.x; o.y += p.y; o.z += p.z; o.w += p.w;
        }
        *(float4*)(P + (size_t)gb * Dn + t * 4) = o;
    }
}

// combine 8 block-partials per batch, normalize.
__global__ __launch_bounds__(256) void k_final(const float* __restrict__ P,
        const float* __restrict__ den, float* __restrict__ out) {
    int b = blockIdx.x, t = threadIdx.x;
    float dtot = 0.f;
    #pragma unroll
    for (int k = 0; k < 8; ++k) dtot += den[b * 8 + k];
    float o = 0.f;
    #pragma unroll
    for (int k = 0; k < 8; ++k) o += P[(size_t)(b * 8 + k) * Dn + t];
    out[(size_t)b * Dn + t] = o / (dtot + EPS_F);
}

extern "C" void kernel_launch(void* const* d_in, const int* in_sizes, int n_in,
                              void* d_out, int out_size, void* d_ws, size_t ws_size,
                              hipStream_t stream) {
    const float* key   = (const float*)d_in[0];
    const float* query = (const float*)d_in[1];
    const int*   mask  = (const int*)d_in[2];
    const float* W     = (const float*)d_in[3];
    const float* bias  = (const float*)d_in[4];
    const float* Wu    = (const float*)d_in[5];
    float* out = (float*)d_out;

    char* ws = (char*)d_ws;
    float*  u   = (float*)(ws);
    ushort* Bhi = (ushort*)(ws + 512);
    float*  Pp  = (float*)(ws + 66048);
    float*  den = (float*)(ws + 1114624);

    hipLaunchKernelGGL(k_prep,   dim3(65),   dim3(256), 0, stream, Wu, query, u, W, Bhi);
    hipLaunchKernelGGL(k_scores, dim3(NBLK), dim3(512), 0, stream,
                       key, Bhi, bias, u, mask, Pp, den);
    hipLaunchKernelGGL(k_final,  dim3(Bn),   dim3(256), 0, stream, Pp, den, out);
}